// Round 1
// baseline (172.655 us; speedup 1.0000x reference)
//
#include <hip/hip_runtime.h>

// Linear attention via bf16 MFMA:
//   KVT[b][v][d] = sum_k V[b,k,v] * (relu(K[b,k,d])+eps)   (fp32 partials over S-chunks)
//   out[b][q,v]  = sum_d (relu(Q[b,q,d])+eps) * KVT[b][v][d]
//
// v2 changes vs baseline (151.8 us):
//  - kvt: double-buffered LDS + software pipeline (issue loads t+2 / pack+write t+1 /
//    MFMA t), raw s_barrier with explicit lgkmcnt(0) so prefetch global loads stay
//    in flight across the barrier (HIP __syncthreads would drain vmcnt(0)).
//  - kvt: XCD-pair block swizzle so the vt=0/1 pair for one (chunk,b) shares an XCD
//    and the K chunk is fetched from HBM once.
//  - out: LDS-free / barrier-free. Q fragments (d contiguous) loaded directly from
//    global as float4 pairs; KVT bf16 fragments as direct 16B loads (L2-resident).
//    Bit-identical math to the staged version.

#define BB 8
#define SS 4096
#define DD 256
#define DDV 256
#define EPSF 1e-6f

typedef short bf16x8 __attribute__((ext_vector_type(8)));
typedef float f32x4 __attribute__((ext_vector_type(4)));

__device__ __forceinline__ unsigned int f2bf(float f) {
  unsigned int u = __float_as_uint(f);
  u += 0x7FFF + ((u >> 16) & 1);   // RNE
  return u >> 16;
}
__device__ __forceinline__ unsigned int pack2(float a, float b) {
  return f2bf(a) | (f2bf(b) << 16);
}

// Raw barrier that does NOT drain vmcnt: LDS writes are made visible via
// lgkmcnt(0); outstanding global loads (the prefetch) stay in flight.
__device__ __forceinline__ void sync_lds() {
  asm volatile("s_waitcnt lgkmcnt(0)" ::: "memory");
  __builtin_amdgcn_s_barrier();
  __builtin_amdgcn_sched_barrier(0);
}

// ---------------- Kernel A: KVT partials ----------------
// grid (nblocks = 2*nchunk*BB), block 512. Tile: 128 v x 256 d, BK=64.
__global__ __launch_bounds__(512, 2) void kvt_kernel(
    const float* __restrict__ K, const float* __restrict__ V,
    float* __restrict__ part, int kchunk) {
  const int nchunk  = SS / kchunk;
  const int nblocks = 2 * nchunk * BB;
  // XCD-pair swizzle: block f runs work w = (f%8)*(nblocks/8) + f/8.
  // Works 2t and 2t+1 (the vt pair of one (chunk,b)) land on blocks whose ids
  // are congruent mod 8 -> same XCD -> K chunk is L2-hit on the second read.
  const int f  = blockIdx.x;
  const int w  = (f & 7) * (nblocks >> 3) + (f >> 3);
  const int vt    = w & 1;
  const int rest  = w >> 1;
  const int chunk = rest % nchunk;
  const int b     = rest / nchunk;
  const int k0blk = chunk * kchunk;

  __shared__ ushort Vt[2][128 * 64];  // [v][k] swizzled, 2 x 16 KB
  __shared__ ushort Kt[2][256 * 64];  // [d][k] swizzled, 2 x 32 KB

  const int tid  = threadIdx.x;
  const int lane = tid & 63;
  const int wid  = tid >> 6;   // 0..7
  const int wv   = wid >> 2;   // 0..1 (v dir)
  const int wd   = wid & 3;    // 0..3 (d dir)

  f32x4 acc[4][4];
  #pragma unroll
  for (int i = 0; i < 4; i++)
    #pragma unroll
    for (int j = 0; j < 4; j++)
      acc[i][j] = (f32x4){0.f, 0.f, 0.f, 0.f};

  const float* Vb = V + (size_t)b * SS * DDV + vt * 128;
  const float* Kb = K + (size_t)b * SS * DD;

  // staging coordinates (fixed per thread)
  const int rv  = tid & 127, obv = tid >> 7;  // V: 128 rows(v), octet base 0..3
  const int rk  = tid & 255, obk = tid >> 8;  // K: 256 rows(d), octet base 0..1

  float fV[2][8];
  float fK[4][8];

  auto issue = [&](int kk) {
    #pragma unroll
    for (int p = 0; p < 2; p++) {
      const int o = obv + p * 4;
      #pragma unroll
      for (int j = 0; j < 8; j++)
        fV[p][j] = Vb[(size_t)(k0blk + kk + o * 8 + j) * DDV + rv];
    }
    #pragma unroll
    for (int p = 0; p < 4; p++) {
      const int o = obk + p * 2;
      #pragma unroll
      for (int j = 0; j < 8; j++)
        fK[p][j] = Kb[(size_t)(k0blk + kk + o * 8 + j) * DD + rk];
    }
    __builtin_amdgcn_sched_barrier(0);  // pin loads here (prefetch position)
  };

  auto packwrite = [&](int buf) {
    #pragma unroll
    for (int p = 0; p < 2; p++) {
      const int o = obv + p * 4;
      uint4 wq;
      wq.x = pack2(fV[p][0], fV[p][1]); wq.y = pack2(fV[p][2], fV[p][3]);
      wq.z = pack2(fV[p][4], fV[p][5]); wq.w = pack2(fV[p][6], fV[p][7]);
      const int co = o ^ (rv & 7);
      *(uint4*)&Vt[buf][rv * 64 + co * 8] = wq;
    }
    #pragma unroll
    for (int p = 0; p < 4; p++) {
      const int o = obk + p * 2;
      float g[8];
      #pragma unroll
      for (int j = 0; j < 8; j++) g[j] = fmaxf(fK[p][j], 0.0f) + EPSF;
      uint4 wq;
      wq.x = pack2(g[0], g[1]); wq.y = pack2(g[2], g[3]);
      wq.z = pack2(g[4], g[5]); wq.w = pack2(g[6], g[7]);
      const int co = o ^ (rk & 7);
      *(uint4*)&Kt[buf][rk * 64 + co * 8] = wq;
    }
  };

  auto mfma_phase = [&](int buf) {
    #pragma unroll
    for (int ks = 0; ks < 2; ks++) {
      const int oct = ks * 4 + (lane >> 4);
      bf16x8 af[4], bfr[4];
      #pragma unroll
      for (int i = 0; i < 4; i++) {
        const int row = wv * 64 + i * 16 + (lane & 15);
        af[i] = *(const bf16x8*)&Vt[buf][row * 64 + (oct ^ (row & 7)) * 8];
      }
      #pragma unroll
      for (int j = 0; j < 4; j++) {
        const int row = wd * 64 + j * 16 + (lane & 15);
        bfr[j] = *(const bf16x8*)&Kt[buf][row * 64 + (oct ^ (row & 7)) * 8];
      }
      #pragma unroll
      for (int i = 0; i < 4; i++)
        #pragma unroll
        for (int j = 0; j < 4; j++)
          acc[i][j] = __builtin_amdgcn_mfma_f32_16x16x32_bf16(af[i], bfr[j], acc[i][j], 0, 0, 0);
    }
  };

  const int nt = kchunk >> 6;
  issue(0);
  packwrite(0);                 // data-dep vmcnt wait inserted by compiler
  if (nt > 1) issue(64);
  sync_lds();

  int cur = 0;
  for (int t = 0; t < nt; t++) {
    mfma_phase(cur);
    if (t + 1 < nt) {
      packwrite(cur ^ 1);       // tile t+1 (loads issued one full iter ago)
      if (t + 2 < nt) issue((t + 2) << 6);
      sync_lds();
    }
    cur ^= 1;
  }

  // epilogue: fp32 partial store, KVT layout [v][d]
  float* pb = part + ((size_t)chunk * BB + b) * (DD * DDV);
  #pragma unroll
  for (int i = 0; i < 4; i++) {
    const int v = vt * 128 + wv * 64 + i * 16 + ((lane >> 4) << 2);
    #pragma unroll
    for (int j = 0; j < 4; j++) {
      const int d = wd * 64 + j * 16 + (lane & 15);
      #pragma unroll
      for (int r = 0; r < 4; r++)
        pb[(size_t)(v + r) * DD + d] = acc[i][j][r];
    }
  }
}

// ---------------- Kernel R: reduce partials -> bf16 KVT ----------------
// grid 512, block 256; each thread: 4 consecutive d.
__global__ __launch_bounds__(256) void reduce_kernel(
    const float* __restrict__ part, ushort* __restrict__ kvb, int nchunk) {
  const size_t N = (size_t)BB * DD * DDV;        // 524288
  const size_t i4 = ((size_t)blockIdx.x * 256 + threadIdx.x) * 4;
  float4 s = make_float4(0.f, 0.f, 0.f, 0.f);
  for (int c = 0; c < nchunk; c++) {
    float4 p = *(const float4*)&part[(size_t)c * N + i4];
    s.x += p.x; s.y += p.y; s.z += p.z; s.w += p.w;
  }
  uint2 o;
  o.x = pack2(s.x, s.y);
  o.y = pack2(s.z, s.w);
  *(uint2*)&kvb[i4] = o;
}

// ---------------- Kernel B: out = (relu(Q)+eps) @ KVT^T ----------------
// grid (64 /*q-tile*/, BB), block 256. Tile: 64 q x 256 v. LDS-free, barrier-free:
// Q fragments direct from global (d contiguous), KVT fragments direct (L2-resident).
__global__ __launch_bounds__(256, 2) void out_kernel(
    const float* __restrict__ Q, const ushort* __restrict__ kvb,
    float* __restrict__ out) {
  const int qt = blockIdx.x;
  const int b  = blockIdx.y;
  const int q0 = qt * 64;

  const int tid  = threadIdx.x;
  const int lane = tid & 63;
  const int wv   = tid >> 6;           // 0..3: v quarter
  const int lq   = lane & 15;
  const int lk   = (lane >> 4) << 3;   // 0,8,16,24: k-offset within the 32-wide step

  f32x4 acc[4][4];
  #pragma unroll
  for (int i = 0; i < 4; i++)
    #pragma unroll
    for (int j = 0; j < 4; j++)
      acc[i][j] = (f32x4){0.f, 0.f, 0.f, 0.f};

  const float*  Qb  = Q   + ((size_t)b * SS + q0) * DD;
  const ushort* KVb = kvb + (size_t)b * DD * DDV;

  #pragma unroll 2
  for (int dc = 0; dc < DD; dc += 32) {
    bf16x8 af[4], bfr[4];
    #pragma unroll
    for (int i = 0; i < 4; i++) {
      const float* p = &Qb[(size_t)(i * 16 + lq) * DD + dc + lk];
      float4 x = *(const float4*)p;
      float4 y = *(const float4*)(p + 4);
      uint4 u;
      u.x = pack2(fmaxf(x.x, 0.f) + EPSF, fmaxf(x.y, 0.f) + EPSF);
      u.y = pack2(fmaxf(x.z, 0.f) + EPSF, fmaxf(x.w, 0.f) + EPSF);
      u.z = pack2(fmaxf(y.x, 0.f) + EPSF, fmaxf(y.y, 0.f) + EPSF);
      u.w = pack2(fmaxf(y.z, 0.f) + EPSF, fmaxf(y.w, 0.f) + EPSF);
      af[i] = *(bf16x8*)&u;
    }
    #pragma unroll
    for (int j = 0; j < 4; j++)
      bfr[j] = *(const bf16x8*)&KVb[(size_t)(wv * 64 + j * 16 + lq) * DD + dc + lk];
    #pragma unroll
    for (int i = 0; i < 4; i++)
      #pragma unroll
      for (int j = 0; j < 4; j++)
        acc[i][j] = __builtin_amdgcn_mfma_f32_16x16x32_bf16(af[i], bfr[j], acc[i][j], 0, 0, 0);
  }

  float* ob = out + ((size_t)b * SS + q0) * DDV;
  #pragma unroll
  for (int i = 0; i < 4; i++) {
    const int qr = i * 16 + ((lane >> 4) << 2);
    #pragma unroll
    for (int j = 0; j < 4; j++) {
      const int v = wv * 64 + j * 16 + lq;
      #pragma unroll
      for (int r = 0; r < 4; r++)
        ob[(size_t)(qr + r) * DDV + v] = acc[i][j][r];
    }
  }
}

extern "C" void kernel_launch(void* const* d_in, const int* in_sizes, int n_in,
                              void* d_out, int out_size, void* d_ws, size_t ws_size,
                              hipStream_t stream) {
  const float* Q = (const float*)d_in[0];
  const float* K = (const float*)d_in[1];
  const float* V = (const float*)d_in[2];
  float* out = (float*)d_out;

  const size_t N = (size_t)BB * DD * DDV;  // 524288 elements
  // ws: [nchunk fp32 partials][bf16 KVT]
  int nchunk = 16;
  while (nchunk > 1 && (size_t)nchunk * N * 4 + N * 2 > ws_size) nchunk >>= 1;
  const int kchunk = SS / nchunk;

  float* part = (float*)d_ws;
  ushort* kvb = (ushort*)(part + (size_t)nchunk * N);

  const int nblocks = 2 * nchunk * BB;
  kvt_kernel<<<dim3(nblocks), 512, 0, stream>>>(K, V, part, kchunk);
  reduce_kernel<<<dim3(512), 256, 0, stream>>>(part, kvb, nchunk);
  out_kernel<<<dim3(SS / 64, BB), 256, 0, stream>>>(Q, kvb, out);
}

// Round 2
// 166.729 us; speedup vs baseline: 1.0355x; 1.0355x over previous
//
#include <hip/hip_runtime.h>

// Linear attention via bf16 MFMA:
//   KVT[b][v][d] = sum_k V[b,k,v] * (relu(K[b,k,d])+eps)   (fp32 partials over S-chunks)
//   out[b][q,v]  = sum_d (relu(Q[b,q,d])+eps) * KVT[b][v][d]
//
// v3 changes vs v2 (172.7 us; out_kernel 50 us latency-bound @ 16% occupancy):
//  - out: 32q x 256v tiles, 256 thr, grid (128,8)=1024 blocks -> 4 blocks/CU,
//    launch_bounds(256,4), full dc unroll for deep load pipelining. Fragments
//    still direct-from-global (KVT is L2-resident; Q lines fully covered).
//  - kvt: split d-dim x2 (not nchunk) -> grid 512, LDS 64 KB -> 2 blocks/CU,
//    keeping the double-buffered no-vmcnt-drain pipeline. XCD swizzle groups
//    all 4 (vt,dt) sub-blocks of one (chunk,b) on one XCD: K and V each hit
//    HBM once per chunk.

#define BB 8
#define SS 4096
#define DD 256
#define DDV 256
#define EPSF 1e-6f

typedef short bf16x8 __attribute__((ext_vector_type(8)));
typedef float f32x4 __attribute__((ext_vector_type(4)));

__device__ __forceinline__ unsigned int f2bf(float f) {
  unsigned int u = __float_as_uint(f);
  u += 0x7FFF + ((u >> 16) & 1);   // RNE
  return u >> 16;
}
__device__ __forceinline__ unsigned int pack2(float a, float b) {
  return f2bf(a) | (f2bf(b) << 16);
}

// Raw barrier that does NOT drain vmcnt: LDS writes are made visible via
// lgkmcnt(0); outstanding global loads (the prefetch) stay in flight.
__device__ __forceinline__ void sync_lds() {
  asm volatile("s_waitcnt lgkmcnt(0)" ::: "memory");
  __builtin_amdgcn_s_barrier();
  __builtin_amdgcn_sched_barrier(0);
}

// ---------------- Kernel A: KVT partials ----------------
// grid 4*nchunk*BB, block 512. Per block: 128 v x 128 d, BK=64 pipeline.
__global__ __launch_bounds__(512, 4) void kvt_kernel(
    const float* __restrict__ K, const float* __restrict__ V,
    float* __restrict__ part, int kchunk) {
  const int nchunk  = SS / kchunk;
  const int nblocks = 4 * nchunk * BB;
  // XCD swizzle: block f runs work w = (f%8)*(nblocks/8) + f/8. The 4 subs
  // (vt,dt) of one (chunk,b) are consecutive w -> same f%8 -> same XCD, so
  // the K and V chunks are fetched from HBM once and L2-hit 3 more times.
  const int f  = blockIdx.x;
  const int w  = (f & 7) * (nblocks >> 3) + (f >> 3);
  const int sub   = w & 3;
  const int vt    = sub & 1;
  const int dt    = sub >> 1;
  const int rest  = w >> 2;
  const int chunk = rest % nchunk;
  const int b     = rest / nchunk;
  const int k0blk = chunk * kchunk;

  __shared__ ushort Vt[2][128 * 64];  // [v][k] swizzled, 2 x 16 KB
  __shared__ ushort Kt[2][128 * 64];  // [d][k] swizzled, 2 x 16 KB

  const int tid  = threadIdx.x;
  const int lane = tid & 63;
  const int wid  = tid >> 6;   // 0..7
  const int wv   = wid >> 2;   // 0..1 (v dir, 64 rows each)
  const int wd   = wid & 3;    // 0..3 (d dir, 32 rows each)

  f32x4 acc[4][2];
  #pragma unroll
  for (int i = 0; i < 4; i++)
    #pragma unroll
    for (int j = 0; j < 2; j++)
      acc[i][j] = (f32x4){0.f, 0.f, 0.f, 0.f};

  const float* Vb = V + (size_t)b * SS * DDV + vt * 128;
  const float* Kb = K + (size_t)b * SS * DD + dt * 128;

  // staging coordinates (fixed per thread): 128 rows x 8 octets, 512 threads
  const int rs = tid & 127, ob = tid >> 7;  // octet base 0..3, p adds 4

  float fV[2][8];
  float fK[2][8];

  auto issue = [&](int kk) {
    #pragma unroll
    for (int p = 0; p < 2; p++) {
      const int o = ob + p * 4;
      #pragma unroll
      for (int j = 0; j < 8; j++)
        fV[p][j] = Vb[(size_t)(k0blk + kk + o * 8 + j) * DDV + rs];
    }
    #pragma unroll
    for (int p = 0; p < 2; p++) {
      const int o = ob + p * 4;
      #pragma unroll
      for (int j = 0; j < 8; j++)
        fK[p][j] = Kb[(size_t)(k0blk + kk + o * 8 + j) * DD + rs];
    }
    __builtin_amdgcn_sched_barrier(0);  // pin loads here (prefetch position)
  };

  auto packwrite = [&](int buf) {
    #pragma unroll
    for (int p = 0; p < 2; p++) {
      const int o = ob + p * 4;
      uint4 wq;
      wq.x = pack2(fV[p][0], fV[p][1]); wq.y = pack2(fV[p][2], fV[p][3]);
      wq.z = pack2(fV[p][4], fV[p][5]); wq.w = pack2(fV[p][6], fV[p][7]);
      const int co = o ^ (rs & 7);
      *(uint4*)&Vt[buf][rs * 64 + co * 8] = wq;
    }
    #pragma unroll
    for (int p = 0; p < 2; p++) {
      const int o = ob + p * 4;
      float g[8];
      #pragma unroll
      for (int j = 0; j < 8; j++) g[j] = fmaxf(fK[p][j], 0.0f) + EPSF;
      uint4 wq;
      wq.x = pack2(g[0], g[1]); wq.y = pack2(g[2], g[3]);
      wq.z = pack2(g[4], g[5]); wq.w = pack2(g[6], g[7]);
      const int co = o ^ (rs & 7);
      *(uint4*)&Kt[buf][rs * 64 + co * 8] = wq;
    }
  };

  auto mfma_phase = [&](int buf) {
    #pragma unroll
    for (int ks = 0; ks < 2; ks++) {
      const int oct = ks * 4 + (lane >> 4);
      bf16x8 af[4], bfr[2];
      #pragma unroll
      for (int i = 0; i < 4; i++) {
        const int row = wv * 64 + i * 16 + (lane & 15);
        af[i] = *(const bf16x8*)&Vt[buf][row * 64 + (oct ^ (row & 7)) * 8];
      }
      #pragma unroll
      for (int j = 0; j < 2; j++) {
        const int row = wd * 32 + j * 16 + (lane & 15);
        bfr[j] = *(const bf16x8*)&Kt[buf][row * 64 + (oct ^ (row & 7)) * 8];
      }
      #pragma unroll
      for (int i = 0; i < 4; i++)
        #pragma unroll
        for (int j = 0; j < 2; j++)
          acc[i][j] = __builtin_amdgcn_mfma_f32_16x16x32_bf16(af[i], bfr[j], acc[i][j], 0, 0, 0);
    }
  };

  const int nt = kchunk >> 6;
  issue(0);
  packwrite(0);                 // data-dep vmcnt wait inserted by compiler
  if (nt > 1) issue(64);
  sync_lds();

  int cur = 0;
  for (int t = 0; t < nt; t++) {
    mfma_phase(cur);
    if (t + 1 < nt) {
      packwrite(cur ^ 1);       // tile t+1 (loads issued one full iter ago)
      if (t + 2 < nt) issue((t + 2) << 6);
      sync_lds();
    }
    cur ^= 1;
  }

  // epilogue: fp32 partial store, KVT layout [v][d]
  float* pb = part + ((size_t)chunk * BB + b) * (DD * DDV);
  #pragma unroll
  for (int i = 0; i < 4; i++) {
    const int v = vt * 128 + wv * 64 + i * 16 + ((lane >> 4) << 2);
    #pragma unroll
    for (int j = 0; j < 2; j++) {
      const int d = dt * 128 + wd * 32 + j * 16 + (lane & 15);
      #pragma unroll
      for (int r = 0; r < 4; r++)
        pb[(size_t)(v + r) * DD + d] = acc[i][j][r];
    }
  }
}

// ---------------- Kernel R: reduce partials -> bf16 KVT ----------------
// grid 512, block 256; each thread: 4 consecutive d.
__global__ __launch_bounds__(256) void reduce_kernel(
    const float* __restrict__ part, ushort* __restrict__ kvb, int nchunk) {
  const size_t N = (size_t)BB * DD * DDV;        // 524288
  const size_t i4 = ((size_t)blockIdx.x * 256 + threadIdx.x) * 4;
  float4 s = make_float4(0.f, 0.f, 0.f, 0.f);
  for (int c = 0; c < nchunk; c++) {
    float4 p = *(const float4*)&part[(size_t)c * N + i4];
    s.x += p.x; s.y += p.y; s.z += p.z; s.w += p.w;
  }
  uint2 o;
  o.x = pack2(s.x, s.y);
  o.y = pack2(s.z, s.w);
  *(uint2*)&kvb[i4] = o;
}

// ---------------- Kernel B: out = (relu(Q)+eps) @ KVT^T ----------------
// grid (128 /*q-tile*/, BB), block 256 -> 1024 blocks, 4 blocks/CU.
// Tile: 32 q x 256 v. LDS-free/barrier-free; fragments direct from global
// (KVT L2-resident; Q 64B lines fully covered by lane pairs). Full dc unroll
// gives the scheduler 64 independent 16B loads to hide latency with.
__global__ __launch_bounds__(256, 4) void out_kernel(
    const float* __restrict__ Q, const ushort* __restrict__ kvb,
    float* __restrict__ out) {
  const int qt = blockIdx.x;
  const int b  = blockIdx.y;
  const int q0 = qt * 32;

  const int tid  = threadIdx.x;
  const int lane = tid & 63;
  const int wv   = tid >> 6;           // 0..3: v quarter
  const int lq   = lane & 15;
  const int lk   = (lane >> 4) << 3;   // 0,8,16,24: k-offset within 32-wide step

  f32x4 acc[2][4];
  #pragma unroll
  for (int i = 0; i < 2; i++)
    #pragma unroll
    for (int j = 0; j < 4; j++)
      acc[i][j] = (f32x4){0.f, 0.f, 0.f, 0.f};

  const float*  Qb  = Q   + ((size_t)b * SS + q0) * DD;
  const ushort* KVb = kvb + (size_t)b * DD * DDV;

  #pragma unroll
  for (int dc = 0; dc < DD; dc += 32) {
    bf16x8 af[2], bfr[4];
    #pragma unroll
    for (int i = 0; i < 2; i++) {
      const float* p = &Qb[(size_t)(i * 16 + lq) * DD + dc + lk];
      float4 x = *(const float4*)p;
      float4 y = *(const float4*)(p + 4);
      uint4 u;
      u.x = pack2(fmaxf(x.x, 0.f) + EPSF, fmaxf(x.y, 0.f) + EPSF);
      u.y = pack2(fmaxf(x.z, 0.f) + EPSF, fmaxf(x.w, 0.f) + EPSF);
      u.z = pack2(fmaxf(y.x, 0.f) + EPSF, fmaxf(y.y, 0.f) + EPSF);
      u.w = pack2(fmaxf(y.z, 0.f) + EPSF, fmaxf(y.w, 0.f) + EPSF);
      af[i] = *(bf16x8*)&u;
    }
    #pragma unroll
    for (int j = 0; j < 4; j++)
      bfr[j] = *(const bf16x8*)&KVb[(size_t)(wv * 64 + j * 16 + lq) * DD + dc + lk];
    #pragma unroll
    for (int i = 0; i < 2; i++)
      #pragma unroll
      for (int j = 0; j < 4; j++)
        acc[i][j] = __builtin_amdgcn_mfma_f32_16x16x32_bf16(af[i], bfr[j], acc[i][j], 0, 0, 0);
  }

  float* ob = out + ((size_t)b * SS + q0) * DDV;
  #pragma unroll
  for (int i = 0; i < 2; i++) {
    const int qr = i * 16 + ((lane >> 4) << 2);
    #pragma unroll
    for (int j = 0; j < 4; j++) {
      const int v = wv * 64 + j * 16 + lq;
      #pragma unroll
      for (int r = 0; r < 4; r++)
        ob[(size_t)(qr + r) * DDV + v] = acc[i][j][r];
    }
  }
}

extern "C" void kernel_launch(void* const* d_in, const int* in_sizes, int n_in,
                              void* d_out, int out_size, void* d_ws, size_t ws_size,
                              hipStream_t stream) {
  const float* Q = (const float*)d_in[0];
  const float* K = (const float*)d_in[1];
  const float* V = (const float*)d_in[2];
  float* out = (float*)d_out;

  const size_t N = (size_t)BB * DD * DDV;  // 524288 elements
  // ws: [nchunk fp32 partials][bf16 KVT]
  int nchunk = 16;
  while (nchunk > 1 && (size_t)nchunk * N * 4 + N * 2 > ws_size) nchunk >>= 1;
  const int kchunk = SS / nchunk;

  float* part = (float*)d_ws;
  ushort* kvb = (ushort*)(part + (size_t)nchunk * N);

  const int nblocks = 4 * nchunk * BB;
  kvt_kernel<<<dim3(nblocks), 512, 0, stream>>>(K, V, part, kchunk);
  reduce_kernel<<<dim3(512), 256, 0, stream>>>(part, kvb, nchunk);
  out_kernel<<<dim3(SS / 32, BB), 256, 0, stream>>>(Q, kvb, out);
}

// Round 3
// 155.935 us; speedup vs baseline: 1.1072x; 1.0692x over previous
//
#include <hip/hip_runtime.h>

// Linear attention via bf16 MFMA:
//   KVT[b][v][d] = sum_k V[b,k,v] * (relu(K[b,k,d])+eps)   (fp32 partials over S-chunks)
//   out[b][q,v]  = sum_d (relu(Q[b,q,d])+eps) * KVT[b][v][d]
//
// v4 changes vs v3 (166.7 us; out_kernel 43 us, latency-bound, VGPR 44, 1:1 load:MFMA):
//  - out: stage the block's 128v x 256d KVT half in LDS ONCE (64 KB, XOR-swizzled),
//    then a barrier-free fully-unrolled MFMA stream: per dc step 2 prefetched global
//    Q loads + 8 conflict-free ds_read_b128 + 8 MFMAs. 512 blocks (2 vt x 32 qt x 8 b),
//    2 blocks/CU. XCD-pair swizzle puts the vt pair of one q-tile on one XCD so the
//    Q tile is HBM-fetched once.
//  - kvt / reduce: unchanged from v3.

#define BB 8
#define SS 4096
#define DD 256
#define DDV 256
#define EPSF 1e-6f

typedef short bf16x8 __attribute__((ext_vector_type(8)));
typedef float f32x4 __attribute__((ext_vector_type(4)));

__device__ __forceinline__ unsigned int f2bf(float f) {
  unsigned int u = __float_as_uint(f);
  u += 0x7FFF + ((u >> 16) & 1);   // RNE
  return u >> 16;
}
__device__ __forceinline__ unsigned int pack2(float a, float b) {
  return f2bf(a) | (f2bf(b) << 16);
}

// Raw barrier that does NOT drain vmcnt: LDS writes are made visible via
// lgkmcnt(0); outstanding global loads (prefetch) stay in flight.
__device__ __forceinline__ void sync_lds() {
  asm volatile("s_waitcnt lgkmcnt(0)" ::: "memory");
  __builtin_amdgcn_s_barrier();
  __builtin_amdgcn_sched_barrier(0);
}

// ---------------- Kernel A: KVT partials ----------------
// grid 4*nchunk*BB, block 512. Per block: 128 v x 128 d, BK=64 pipeline.
__global__ __launch_bounds__(512, 4) void kvt_kernel(
    const float* __restrict__ K, const float* __restrict__ V,
    float* __restrict__ part, int kchunk) {
  const int nchunk  = SS / kchunk;
  const int nblocks = 4 * nchunk * BB;
  // XCD swizzle: block f runs work w = (f%8)*(nblocks/8) + f/8. The 4 subs
  // (vt,dt) of one (chunk,b) are consecutive w -> same f%8 -> same XCD, so
  // the K and V chunks are fetched from HBM once and L2-hit 3 more times.
  const int f  = blockIdx.x;
  const int w  = (f & 7) * (nblocks >> 3) + (f >> 3);
  const int sub   = w & 3;
  const int vt    = sub & 1;
  const int dt    = sub >> 1;
  const int rest  = w >> 2;
  const int chunk = rest % nchunk;
  const int b     = rest / nchunk;
  const int k0blk = chunk * kchunk;

  __shared__ ushort Vt[2][128 * 64];  // [v][k] swizzled, 2 x 16 KB
  __shared__ ushort Kt[2][128 * 64];  // [d][k] swizzled, 2 x 16 KB

  const int tid  = threadIdx.x;
  const int lane = tid & 63;
  const int wid  = tid >> 6;   // 0..7
  const int wv   = wid >> 2;   // 0..1 (v dir, 64 rows each)
  const int wd   = wid & 3;    // 0..3 (d dir, 32 rows each)

  f32x4 acc[4][2];
  #pragma unroll
  for (int i = 0; i < 4; i++)
    #pragma unroll
    for (int j = 0; j < 2; j++)
      acc[i][j] = (f32x4){0.f, 0.f, 0.f, 0.f};

  const float* Vb = V + (size_t)b * SS * DDV + vt * 128;
  const float* Kb = K + (size_t)b * SS * DD + dt * 128;

  // staging coordinates (fixed per thread): 128 rows x 8 octets, 512 threads
  const int rs = tid & 127, ob = tid >> 7;  // octet base 0..3, p adds 4

  float fV[2][8];
  float fK[2][8];

  auto issue = [&](int kk) {
    #pragma unroll
    for (int p = 0; p < 2; p++) {
      const int o = ob + p * 4;
      #pragma unroll
      for (int j = 0; j < 8; j++)
        fV[p][j] = Vb[(size_t)(k0blk + kk + o * 8 + j) * DDV + rs];
    }
    #pragma unroll
    for (int p = 0; p < 2; p++) {
      const int o = ob + p * 4;
      #pragma unroll
      for (int j = 0; j < 8; j++)
        fK[p][j] = Kb[(size_t)(k0blk + kk + o * 8 + j) * DD + rs];
    }
    __builtin_amdgcn_sched_barrier(0);  // pin loads here (prefetch position)
  };

  auto packwrite = [&](int buf) {
    #pragma unroll
    for (int p = 0; p < 2; p++) {
      const int o = ob + p * 4;
      uint4 wq;
      wq.x = pack2(fV[p][0], fV[p][1]); wq.y = pack2(fV[p][2], fV[p][3]);
      wq.z = pack2(fV[p][4], fV[p][5]); wq.w = pack2(fV[p][6], fV[p][7]);
      const int co = o ^ (rs & 7);
      *(uint4*)&Vt[buf][rs * 64 + co * 8] = wq;
    }
    #pragma unroll
    for (int p = 0; p < 2; p++) {
      const int o = ob + p * 4;
      float g[8];
      #pragma unroll
      for (int j = 0; j < 8; j++) g[j] = fmaxf(fK[p][j], 0.0f) + EPSF;
      uint4 wq;
      wq.x = pack2(g[0], g[1]); wq.y = pack2(g[2], g[3]);
      wq.z = pack2(g[4], g[5]); wq.w = pack2(g[6], g[7]);
      const int co = o ^ (rs & 7);
      *(uint4*)&Kt[buf][rs * 64 + co * 8] = wq;
    }
  };

  auto mfma_phase = [&](int buf) {
    #pragma unroll
    for (int ks = 0; ks < 2; ks++) {
      const int oct = ks * 4 + (lane >> 4);
      bf16x8 af[4], bfr[2];
      #pragma unroll
      for (int i = 0; i < 4; i++) {
        const int row = wv * 64 + i * 16 + (lane & 15);
        af[i] = *(const bf16x8*)&Vt[buf][row * 64 + (oct ^ (row & 7)) * 8];
      }
      #pragma unroll
      for (int j = 0; j < 2; j++) {
        const int row = wd * 32 + j * 16 + (lane & 15);
        bfr[j] = *(const bf16x8*)&Kt[buf][row * 64 + (oct ^ (row & 7)) * 8];
      }
      #pragma unroll
      for (int i = 0; i < 4; i++)
        #pragma unroll
        for (int j = 0; j < 2; j++)
          acc[i][j] = __builtin_amdgcn_mfma_f32_16x16x32_bf16(af[i], bfr[j], acc[i][j], 0, 0, 0);
    }
  };

  const int nt = kchunk >> 6;
  issue(0);
  packwrite(0);                 // data-dep vmcnt wait inserted by compiler
  if (nt > 1) issue(64);
  sync_lds();

  int cur = 0;
  for (int t = 0; t < nt; t++) {
    mfma_phase(cur);
    if (t + 1 < nt) {
      packwrite(cur ^ 1);       // tile t+1 (loads issued one full iter ago)
      if (t + 2 < nt) issue((t + 2) << 6);
      sync_lds();
    }
    cur ^= 1;
  }

  // epilogue: fp32 partial store, KVT layout [v][d]
  float* pb = part + ((size_t)chunk * BB + b) * (DD * DDV);
  #pragma unroll
  for (int i = 0; i < 4; i++) {
    const int v = vt * 128 + wv * 64 + i * 16 + ((lane >> 4) << 2);
    #pragma unroll
    for (int j = 0; j < 2; j++) {
      const int d = dt * 128 + wd * 32 + j * 16 + (lane & 15);
      #pragma unroll
      for (int r = 0; r < 4; r++)
        pb[(size_t)(v + r) * DD + d] = acc[i][j][r];
    }
  }
}

// ---------------- Kernel R: reduce partials -> bf16 KVT ----------------
// grid 512, block 256; each thread: 4 consecutive d.
__global__ __launch_bounds__(256) void reduce_kernel(
    const float* __restrict__ part, ushort* __restrict__ kvb, int nchunk) {
  const size_t N = (size_t)BB * DD * DDV;        // 524288
  const size_t i4 = ((size_t)blockIdx.x * 256 + threadIdx.x) * 4;
  float4 s = make_float4(0.f, 0.f, 0.f, 0.f);
  for (int c = 0; c < nchunk; c++) {
    float4 p = *(const float4*)&part[(size_t)c * N + i4];
    s.x += p.x; s.y += p.y; s.z += p.z; s.w += p.w;
  }
  uint2 o;
  o.x = pack2(s.x, s.y);
  o.y = pack2(s.z, s.w);
  *(uint2*)&kvb[i4] = o;
}

// ---------------- Kernel B: out = (relu(Q)+eps) @ KVT^T ----------------
// grid 512 (= 2 vt x 32 qt x 8 b, XCD-pair swizzled), block 512 (8 waves).
// Stage KVT half (128v x 256d bf16 = 64 KB) in LDS once, then barrier-free:
// each wave owns 16 q rows; 8 unrolled dc steps of {2 prefetched global Q
// loads, 8 swizzled ds_read_b128, 8 MFMA}.
__global__ __launch_bounds__(512, 4) void out_kernel(
    const float* __restrict__ Q, const ushort* __restrict__ kvb,
    float* __restrict__ out) {
  // XCD-pair swizzle: works 2t (vt=0) and 2t+1 (vt=1) of one (qt,b) map to
  // blocks f and f+8 -> same XCD -> shared Q tile is L2-hit on second read.
  const int f  = blockIdx.x;
  const int w  = (f & 7) * 64 + (f >> 3);   // nblocks = 512
  const int vt   = w & 1;
  const int rest = w >> 1;     // 0..255
  const int qt   = rest & 31;
  const int b    = rest >> 5;
  const int q0   = qt * 128;

  __shared__ ushort KVs[128 * 256];  // [v-local][d], 16B-chunk XOR swizzle, 64 KB

  const int tid  = threadIdx.x;
  const int lane = tid & 63;
  const int wq   = tid >> 6;           // wave 0..7 -> q sub-tile (16 rows)
  const int lq   = lane & 15;
  const int lk   = (lane >> 4) << 3;   // 0,8,16,24

  const float* Qw = Q + ((size_t)b * SS + q0 + wq * 16) * DD;

  // prefetch first Q fragment (raw) before staging; sync_lds won't drain it
  float4 x0 = *(const float4*)&Qw[(size_t)lq * DD + lk];
  float4 y0 = *(const float4*)&Qw[(size_t)lq * DD + lk + 4];

  // ---- stage KVT half into LDS (coalesced 16B chunks, swizzled dest) ----
  {
    const ushort* src = kvb + (size_t)b * DD * DDV + (size_t)vt * 128 * DD;
    #pragma unroll
    for (int p = 0; p < 8; p++) {
      const int chunk = p * 512 + tid;     // 4096 chunks of 16B
      const int row = chunk >> 5;          // 0..127 (v-local)
      const int c   = chunk & 31;          // 16B chunk within row
      uint4 val = *(const uint4*)&src[row * DD + c * 8];
      const int cs = c ^ (row & 7);
      *(uint4*)&KVs[row * DD + cs * 8] = val;
    }
  }

  f32x4 acc[8];
  #pragma unroll
  for (int j = 0; j < 8; j++) acc[j] = (f32x4){0.f, 0.f, 0.f, 0.f};

  sync_lds();

  #pragma unroll
  for (int s = 0; s < 8; s++) {
    float4 xn, yn;
    if (s < 7) {
      const float* p = &Qw[(size_t)lq * DD + (s + 1) * 32 + lk];
      xn = *(const float4*)p;
      yn = *(const float4*)(p + 4);
    }
    uint4 u;
    u.x = pack2(fmaxf(x0.x, 0.f) + EPSF, fmaxf(x0.y, 0.f) + EPSF);
    u.y = pack2(fmaxf(x0.z, 0.f) + EPSF, fmaxf(x0.w, 0.f) + EPSF);
    u.z = pack2(fmaxf(y0.x, 0.f) + EPSF, fmaxf(y0.y, 0.f) + EPSF);
    u.w = pack2(fmaxf(y0.z, 0.f) + EPSF, fmaxf(y0.w, 0.f) + EPSF);
    const bf16x8 af = *(bf16x8*)&u;

    bf16x8 bfr[8];
    const int oct = s * 4 + (lane >> 4);
    #pragma unroll
    for (int j = 0; j < 8; j++) {
      const int row = j * 16 + lq;
      bfr[j] = *(const bf16x8*)&KVs[row * DD + ((oct ^ (row & 7)) << 3)];
    }
    #pragma unroll
    for (int j = 0; j < 8; j++)
      acc[j] = __builtin_amdgcn_mfma_f32_16x16x32_bf16(af, bfr[j], acc[j], 0, 0, 0);

    x0 = xn; y0 = yn;
  }

  float* ob = out + ((size_t)b * SS + q0 + wq * 16) * DDV;
  const int qr = (lane >> 4) << 2;
  #pragma unroll
  for (int j = 0; j < 8; j++) {
    const int v = vt * 128 + j * 16 + lq;
    #pragma unroll
    for (int r = 0; r < 4; r++)
      ob[(size_t)(qr + r) * DDV + v] = acc[j][r];
  }
}

extern "C" void kernel_launch(void* const* d_in, const int* in_sizes, int n_in,
                              void* d_out, int out_size, void* d_ws, size_t ws_size,
                              hipStream_t stream) {
  const float* Q = (const float*)d_in[0];
  const float* K = (const float*)d_in[1];
  const float* V = (const float*)d_in[2];
  float* out = (float*)d_out;

  const size_t N = (size_t)BB * DD * DDV;  // 524288 elements
  // ws: [nchunk fp32 partials][bf16 KVT]
  int nchunk = 16;
  while (nchunk > 1 && (size_t)nchunk * N * 4 + N * 2 > ws_size) nchunk >>= 1;
  const int kchunk = SS / nchunk;

  float* part = (float*)d_ws;
  ushort* kvb = (ushort*)(part + (size_t)nchunk * N);

  const int nblocks = 4 * nchunk * BB;
  kvt_kernel<<<dim3(nblocks), 512, 0, stream>>>(K, V, part, kchunk);
  reduce_kernel<<<dim3(512), 256, 0, stream>>>(part, kvb, nchunk);
  out_kernel<<<dim3(512), 512, 0, stream>>>(Q, kvb, out);
}